// Round 7
// baseline (280.628 us; speedup 1.0000x reference)
//
#include <hip/hip_runtime.h>
#include <stdint.h>

typedef unsigned short u16;
typedef unsigned int u32;

using bf16x8 = __attribute__((ext_vector_type(8))) short;
using f32x4  = __attribute__((ext_vector_type(4))) float;

#define DEVINL __device__ __forceinline__

DEVINL float b2f(u16 u) { return __builtin_bit_cast(float, (u32)u << 16); }
DEVINL u16 f2b(float f) {
  u32 u = __builtin_bit_cast(u32, f);
  u += 0x7FFFu + ((u >> 16) & 1u);   // round-to-nearest-even
  return (u16)(u >> 16);
}

DEVINL void gll16(const u16* src, u16* dst) {
  __builtin_amdgcn_global_load_lds(
      (const __attribute__((address_space(1))) void*)(uintptr_t)src,
      (__attribute__((address_space(3))) void*)(uintptr_t)dst, 16, 0, 0);
}

#define MFMA __builtin_amdgcn_mfma_f32_16x16x32_bf16

// ---------------------------------------------------------------- fused convert+transpose
DEVINL void tp_tile(const float* __restrict__ s, u16* __restrict__ d,
                    int R, int C, int bx, int by, int z)
{
  __shared__ u16 tile[32][33];
  const size_t mstride = (size_t)R * C;
  s += (size_t)z * mstride;
  d += (size_t)z * mstride;
  int r0 = bx * 32, c0 = by * 32;
  int tx = threadIdx.x & 31, ty = threadIdx.x >> 5;
#pragma unroll
  for (int i = 0; i < 32; i += 8)
    tile[ty + i][tx] = f2b(s[(size_t)(r0 + ty + i) * C + (c0 + tx)]);
  __syncthreads();
#pragma unroll
  for (int i = 0; i < 32; i += 8)
    d[(size_t)(c0 + ty + i) * R + (r0 + tx)] = tile[tx][ty + i];
}

__global__ __launch_bounds__(256) void transpose_all(
    const float* W0, const float* W1, const float* Wr0, const float* Wr1, const float* Wh0,
    u16* W0t, u16* W1t, u16* Wr0t, u16* Wr1t, u16* Wh0t)
{
  int b = blockIdx.x;
  if (b < 128)      {            tp_tile(W0, W0t, 256, 512, b % 8,  b / 8, 0); }
  else if (b < 384) { b -= 128;  tp_tile(W1, W1t, 512, 512, b % 16, b / 16, 0); }
  else if (b < 576) { b -= 384;  int t = b / 8;  tp_tile(Wr0, Wr0t, 256, 128, b % 8,  t % 4,  t / 4); }
  else if (b < 960) { b -= 576;  int t = b / 4;  tp_tile(Wr1, Wr1t, 128, 512, b % 4,  t % 16, t / 16); }
  else              { b -= 960;  int t = b / 16; tp_tile(Wh0, Wh0t, 512, 64,  b % 16, t % 2,  t / 2); }
}

// ---------------------------------------------------------------- obs layernorm (f32 in, bf16 out)
__global__ __launch_bounds__(256) void ln_f32_256(
    const float* __restrict__ X, const float* __restrict__ sc,
    const float* __restrict__ bi, u16* __restrict__ Y, int nrows)
{
  constexpr int D = 256, PER = 4;
  int lane = threadIdx.x & 63;
  int row = blockIdx.x * 4 + (threadIdx.x >> 6);
  if (row >= nrows) return;
  const float* xr = X + (size_t)row * D + lane * PER;
  float x[PER] __attribute__((aligned(16)));
  *(float4*)x = *(const float4*)xr;
  float s = 0.f, s2 = 0.f;
#pragma unroll
  for (int p = 0; p < PER; ++p) { s += x[p]; s2 += x[p] * x[p]; }
#pragma unroll
  for (int o = 32; o > 0; o >>= 1) { s += __shfl_xor(s, o, 64); s2 += __shfl_xor(s2, o, 64); }
  float m = s * (1.f / D);
  float v = s2 * (1.f / D) - m * m;
  float inv = rsqrtf(v + 1e-5f);
  u16 yu[PER] __attribute__((aligned(8)));
#pragma unroll
  for (int p = 0; p < PER; ++p)
    yu[p] = f2b((x[p] - m) * inv * sc[lane * PER + p] + bi[lane * PER + p]);
  *(uint2*)(Y + (size_t)row * D + lane * PER) = *(uint2*)yu;
}

// ---------------------------------------------------------------- role bucketing
#define NROLE 6
__global__ __launch_bounds__(256) void role_count(
    const int* __restrict__ rid, int* __restrict__ blkCnt)
{
  __shared__ int h[NROLE];
  if (threadIdx.x < NROLE) h[threadIdx.x] = 0;
  __syncthreads();
  int i = blockIdx.x * 256 + threadIdx.x;
  atomicAdd(&h[rid[i]], 1);
  __syncthreads();
  if (threadIdx.x < NROLE) blkCnt[blockIdx.x * NROLE + threadIdx.x] = h[threadIdx.x];
}

__global__ __launch_bounds__(256) void role_scan(
    const int* __restrict__ blkCnt, int* __restrict__ blkBase,
    int* __restrict__ baseArr, int* __restrict__ cntArr)
{
  __shared__ int c[128 * NROLE];
  __shared__ int bb[128 * NROLE];
  __shared__ int sbase[NROLE], scnt[NROLE];
  for (int i = threadIdx.x; i < 128 * NROLE; i += 256) c[i] = blkCnt[i];
  __syncthreads();
  if (threadIdx.x < NROLE) {
    int k = threadIdx.x, run = 0;
    for (int b = 0; b < 128; ++b) { bb[b * NROLE + k] = run; run += c[b * NROLE + k]; }
    scnt[k] = run;
  }
  __syncthreads();
  if (threadIdx.x == 0) {
    int r = 0;
    for (int k = 0; k < NROLE; ++k) { sbase[k] = r; r += scnt[k]; }
  }
  __syncthreads();
  if (threadIdx.x < NROLE) { baseArr[threadIdx.x] = sbase[threadIdx.x]; cntArr[threadIdx.x] = scnt[threadIdx.x]; }
  for (int i = threadIdx.x; i < 128 * NROLE; i += 256)
    blkBase[i] = bb[i] + sbase[i % NROLE];
}

__global__ __launch_bounds__(256) void role_fill(
    const int* __restrict__ rid, const int* __restrict__ blkBase, int* __restrict__ bucket)
{
  __shared__ int h[NROLE];
  if (threadIdx.x < NROLE) h[threadIdx.x] = 0;
  __syncthreads();
  int i = blockIdx.x * 256 + threadIdx.x;
  int k = rid[i];
  int pos = atomicAdd(&h[k], 1);
  bucket[blkBase[blockIdx.x * NROLE + k] + pos] = i;
}

// ---------------------------------------------------------------- fused dense GEMM + ReLU + LN
// C[M x 512] = LN(relu(A[M x K] @ Bt[512 x K]^T + bias)). BM=64, 256 thr,
// 4 waves x 128 cols, acc[4][8]. A double-buffered in LDS; B register-prefetched
// one 32-K chunk ahead, direct from global (L2-resident weights).
template <int K>
__global__ __launch_bounds__(256, 2) void gemm_ln(
    const u16* __restrict__ A, const u16* __restrict__ Bt,
    const float* __restrict__ bias, const float* __restrict__ lnsc,
    const float* __restrict__ lnbi, u16* __restrict__ C)
{
  constexpr int BK = 64, NI = K / BK;
  __shared__ __align__(16) u16 As[2][64 * BK];   // 2 x 8 KB
  __shared__ float redS[64][4];
  __shared__ float redSS[64][4];
  __shared__ float prm[1536];                     // bias | sc | bi
  const int tid = threadIdx.x;
  const int rowBase = blockIdx.x * 64;
  const int lane = tid & 63, wave = tid >> 6;
#pragma unroll
  for (int i = tid; i < 512; i += 256) {
    prm[i] = bias[i]; prm[512 + i] = lnsc[i]; prm[1024 + i] = lnbi[i];
  }
  u32 aOff[2];
#pragma unroll
  for (int r = 0; r < 2; ++r) {
    int row = r * 32 + (tid >> 3);
    aOff[r] = (u32)(rowBase + row) * (u32)K + (u32)(((tid & 7) ^ (row & 7)) * 8);
  }
  const int quad = lane >> 4, lm = lane & 15, l7 = lm & 7;
  const int wn = wave * 128;
  u32 bOff[8];
#pragma unroll
  for (int j = 0; j < 8; ++j)
    bOff[j] = (u32)(wn + j * 16 + lm) * (u32)K + (u32)(quad * 8);

  f32x4 acc[4][8] = {};

#pragma unroll
  for (int r = 0; r < 2; ++r)
    gll16(A + aOff[r], &As[0][r * 2048 + wave * 512]);
  bf16x8 bP[8];
#pragma unroll
  for (int j = 0; j < 8; ++j)
    bP[j] = *(const bf16x8*)(Bt + bOff[j]);
  __syncthreads();

  for (int i = 0; i < NI; ++i) {
    const u16* Ab = As[i & 1];
    if (i + 1 < NI) {
#pragma unroll
      for (int r = 0; r < 2; ++r)
        gll16(A + aOff[r] + (i + 1) * BK, &As[(i + 1) & 1][r * 2048 + wave * 512]);
    }
    bf16x8 bN[8];
#pragma unroll
    for (int j = 0; j < 8; ++j)
      bN[j] = *(const bf16x8*)(Bt + bOff[j] + i * BK + 32);
    bf16x8 af[4];
#pragma unroll
    for (int i2 = 0; i2 < 4; ++i2)
      af[i2] = *(const bf16x8*)&Ab[(i2 * 16 + lm) * 64 + ((quad ^ l7) * 8)];
#pragma unroll
    for (int i2 = 0; i2 < 4; ++i2)
#pragma unroll
      for (int j = 0; j < 8; ++j)
        acc[i2][j] = MFMA(af[i2], bP[j], acc[i2][j], 0, 0, 0);
    if (i + 1 < NI) {
#pragma unroll
      for (int j = 0; j < 8; ++j)
        bP[j] = *(const bf16x8*)(Bt + bOff[j] + (i + 1) * BK);
    }
#pragma unroll
    for (int i2 = 0; i2 < 4; ++i2)
      af[i2] = *(const bf16x8*)&Ab[(i2 * 16 + lm) * 64 + (((quad + 4) ^ l7) * 8)];
#pragma unroll
    for (int i2 = 0; i2 < 4; ++i2)
#pragma unroll
      for (int j = 0; j < 8; ++j)
        acc[i2][j] = MFMA(af[i2], bN[j], acc[i2][j], 0, 0, 0);
    __syncthreads();
  }

#pragma unroll
  for (int i2 = 0; i2 < 4; ++i2) {
#pragma unroll
    for (int r2 = 0; r2 < 4; ++r2) {
      float s = 0.f, ss = 0.f;
#pragma unroll
      for (int j = 0; j < 8; ++j) {
        float v = fmaxf(acc[i2][j][r2] + prm[wn + j * 16 + lm], 0.f);
        acc[i2][j][r2] = v;
        s += v; ss += v * v;
      }
#pragma unroll
      for (int o = 1; o < 16; o <<= 1) { s += __shfl_xor(s, o, 64); ss += __shfl_xor(ss, o, 64); }
      if (lm == 0) {
        int rowL = i2 * 16 + quad * 4 + r2;
        redS[rowL][wave] = s;
        redSS[rowL][wave] = ss;
      }
    }
  }
  __syncthreads();
#pragma unroll
  for (int i2 = 0; i2 < 4; ++i2) {
#pragma unroll
    for (int r2 = 0; r2 < 4; ++r2) {
      int rowL = i2 * 16 + quad * 4 + r2;
      float ts  = redS[rowL][0] + redS[rowL][1] + redS[rowL][2] + redS[rowL][3];
      float tss = redSS[rowL][0] + redSS[rowL][1] + redSS[rowL][2] + redSS[rowL][3];
      float m = ts * (1.f / 512.f);
      float var = tss * (1.f / 512.f) - m * m;
      float inv = rsqrtf(var + 1e-5f);
      size_t base = (size_t)(rowBase + rowL) * 512;
#pragma unroll
      for (int j = 0; j < 8; ++j) {
        int col = wn + j * 16 + lm;
        float y = (acc[i2][j][r2] - m) * inv * prm[512 + col] + prm[1024 + col];
        C[base + col] = f2b(y);
      }
    }
  }
}

// ---------------------------------------------------------------- fused role route + head (full)
// All global gathers (obs_n 16KB + e 32KB) staged via global_load_lds up front,
// draining at ONE barrier. Mid-chain global traffic = L2-hot weights only,
// register-prefetched. LDS (u16 idx): e/ea [0,16384) | A0/h0s [16384,24576) | r1 [24576,28672)
__global__ __launch_bounds__(256, 2) void route_head(
    const u16* __restrict__ obs_n, const u16* __restrict__ e,
    const u16* __restrict__ Wr0t, const float* __restrict__ br0,
    const u16* __restrict__ Wr1t, const float* __restrict__ br1,
    const u16* __restrict__ Wh0t, const float* __restrict__ bh0,
    const float* __restrict__ Wh1, const float* __restrict__ bh1,
    const float* __restrict__ Wh2, const float* __restrict__ bh2,
    const float* __restrict__ avail,
    const int* __restrict__ bucket, const int* __restrict__ baseArr,
    const int* __restrict__ cntArr, float* __restrict__ outLogits)
{
  __shared__ __align__(16) u16 sm[28672];
  __shared__ float prm[704];        // br0 128 | br1 512 | bh0 64
  __shared__ float h1s[32 * 36];
  const int tid = threadIdx.x;

  int role = 0, rem = blockIdx.x, cnt;
  for (;;) {
    cnt = cntArr[role];
    int tiles = (cnt + 31) >> 5;
    if (rem < tiles) break;
    rem -= tiles;
    if (++role >= NROLE) return;
  }
  const int limit = cnt;
  const int rowBase = rem * 32;
  const int roleBase = baseArr[role];

  const int lane = tid & 63, wave = tid >> 6;
  const int quad = lane >> 4, lm = lane & 15, l7 = lm & 7;

  // ---- gather A0 (32x256 obs_n) -> sm[16384..), 4 rounds of 8 rows
#pragma unroll
  for (int r = 0; r < 4; ++r) {
    int lrow = r * 8 + (tid >> 5);
    int i = rowBase + lrow;
    if (i >= limit) i = rowBase;
    int grow = bucket[roleBase + i];
    gll16(obs_n + (u32)grow * 256u + (u32)(((tid & 31) ^ (lrow & 7)) * 8),
          &sm[16384 + r * 2048 + wave * 512]);
  }
  // ---- gather e (32x512) -> sm[0..16384), 8 rounds of 4 rows (same barrier drain)
#pragma unroll
  for (int r = 0; r < 8; ++r) {
    int lrow = r * 4 + wave;
    int i = rowBase + lrow;
    if (i >= limit) i = rowBase;
    int grow = bucket[roleBase + i];
    int chunk = tid & 63;
    int sw = (chunk & 56) | ((chunk ^ lrow) & 7);
    gll16(e + (u32)grow * 512u + (u32)(sw * 8),
          &sm[r * 2048 + wave * 512]);
  }
  {
    if (tid < 128) prm[tid] = br0[role * 128 + tid];
    for (int i = tid; i < 512; i += 256) prm[128 + i] = br1[role * 512 + i];
    if (tid < 64) prm[640 + tid] = bh0[role * 64 + tid];
  }
  __syncthreads();   // single drain for all staging

  // ---- stage0: r1 = relu(A0 @ Wr0k^T + br0)   (N=128, wave covers 32 cols)
  const int wn0 = wave * 32;
  const u16* B0 = Wr0t + (size_t)role * 128 * 256;
  f32x4 acc0[2][2] = {};
  bf16x8 b0P[2];
#pragma unroll
  for (int j = 0; j < 2; ++j)
    b0P[j] = *(const bf16x8*)(B0 + (u32)(wn0 + j * 16 + lm) * 256u + (u32)(quad * 8));
#pragma unroll
  for (int kk = 0; kk < 256; kk += 32) {
    bf16x8 b0N[2];
    if (kk + 32 < 256) {
#pragma unroll
      for (int j = 0; j < 2; ++j)
        b0N[j] = *(const bf16x8*)(B0 + (u32)(wn0 + j * 16 + lm) * 256u + (u32)(quad * 8 + kk + 32));
    }
    const int kc = kk >> 3;
    bf16x8 af[2];
#pragma unroll
    for (int i2 = 0; i2 < 2; ++i2)
      af[i2] = *(const bf16x8*)&sm[16384 + (i2 * 16 + lm) * 256 + (((quad + kc) ^ l7) * 8)];
#pragma unroll
    for (int i2 = 0; i2 < 2; ++i2)
#pragma unroll
      for (int j = 0; j < 2; ++j)
        acc0[i2][j] = MFMA(af[i2], b0P[j], acc0[i2][j], 0, 0, 0);
    if (kk + 32 < 256) { b0P[0] = b0N[0]; b0P[1] = b0N[1]; }
  }
  u16* r1 = sm + 24576;
#pragma unroll
  for (int i2 = 0; i2 < 2; ++i2) {
#pragma unroll
    for (int r2 = 0; r2 < 4; ++r2) {
      int row = i2 * 16 + quad * 4 + r2;
#pragma unroll
      for (int j = 0; j < 2; ++j) {
        int col = wn0 + j * 16 + lm;
        float v = fmaxf(acc0[i2][j][r2] + prm[col], 0.f);
        r1[row * 128 + (((col >> 3) ^ (row & 7)) * 8) + (col & 7)] = f2b(v);
      }
    }
  }
  __syncthreads();

  // ---- stage1: ea = relu(r1 @ Wr1k^T + br1) + e   (N=512, in-place over e in LDS)
  const int wn1 = wave * 128;
  const u16* B1 = Wr1t + (size_t)role * 512 * 128;
  f32x4 acc1[2][8] = {};
  bf16x8 b1P[8];
#pragma unroll
  for (int j = 0; j < 8; ++j)
    b1P[j] = *(const bf16x8*)(B1 + (u32)(wn1 + j * 16 + lm) * 128u + (u32)(quad * 8));
#pragma unroll
  for (int kk = 0; kk < 128; kk += 32) {
    bf16x8 b1N[8];
    if (kk + 32 < 128) {
#pragma unroll
      for (int j = 0; j < 8; ++j)
        b1N[j] = *(const bf16x8*)(B1 + (u32)(wn1 + j * 16 + lm) * 128u + (u32)(quad * 8 + kk + 32));
    }
    const int kc = kk >> 3;
    bf16x8 af[2];
#pragma unroll
    for (int i2 = 0; i2 < 2; ++i2)
      af[i2] = *(const bf16x8*)&r1[(i2 * 16 + lm) * 128 + (((quad + kc) ^ l7) * 8)];
#pragma unroll
    for (int i2 = 0; i2 < 2; ++i2)
#pragma unroll
      for (int j = 0; j < 8; ++j)
        acc1[i2][j] = MFMA(af[i2], b1P[j], acc1[i2][j], 0, 0, 0);
    if (kk + 32 < 128) {
#pragma unroll
      for (int j = 0; j < 8; ++j) b1P[j] = b1N[j];
    }
  }
#pragma unroll
  for (int i2 = 0; i2 < 2; ++i2) {
#pragma unroll
    for (int r2 = 0; r2 < 4; ++r2) {
      int row = i2 * 16 + quad * 4 + r2;
#pragma unroll
      for (int j = 0; j < 8; ++j) {
        int col = wn1 + j * 16 + lm;
        int addr = row * 512 + (((col >> 3) ^ (row & 7)) * 8) + (col & 7);
        float v = fmaxf(acc1[i2][j][r2] + prm[128 + col], 0.f) + b2f(sm[addr]);
        sm[addr] = f2b(v);
      }
    }
  }
  __syncthreads();

  // ---- stage2: h0 = relu(ea @ Wh0k^T + bh0)   (N=64, wave covers 16 cols) -> LDS
  const int wn2 = wave * 16;
  const u16* B2 = Wh0t + (size_t)role * 64 * 512;
  f32x4 acc2[2] = {};
  bf16x8 b2P = *(const bf16x8*)(B2 + (u32)(wn2 + lm) * 512u + (u32)(quad * 8));
#pragma unroll
  for (int kk = 0; kk < 512; kk += 32) {
    bf16x8 b2N;
    if (kk + 32 < 512)
      b2N = *(const bf16x8*)(B2 + (u32)(wn2 + lm) * 512u + (u32)(quad * 8 + kk + 32));
    const int kc = kk >> 3;
    bf16x8 af[2];
#pragma unroll
    for (int i2 = 0; i2 < 2; ++i2)
      af[i2] = *(const bf16x8*)&sm[(i2 * 16 + lm) * 512 + (((quad + kc) ^ l7) * 8)];
#pragma unroll
    for (int i2 = 0; i2 < 2; ++i2)
      acc2[i2] = MFMA(af[i2], b2P, acc2[i2], 0, 0, 0);
    if (kk + 32 < 512) b2P = b2N;
  }
  u16* h0s = sm + 16384;   // A0 region, dead now; 32 rows x stride 68
#pragma unroll
  for (int i2 = 0; i2 < 2; ++i2) {
#pragma unroll
    for (int r2 = 0; r2 < 4; ++r2) {
      int row = i2 * 16 + quad * 4 + r2;
      int col = wn2 + lm;
      h0s[row * 68 + col] = f2b(fmaxf(acc2[i2][r2] + prm[640 + col], 0.f));
    }
  }
  __syncthreads();

  // ---- stage3: per-thread tail. thread t -> row r=t>>3, 4 cols n0=(t&7)*4
  {
    const int r = tid >> 3;
    const int n0 = (tid & 7) * 4;
    const bool valid = (rowBase + r) < limit;
    const float* W1k = Wh1 + (size_t)role * 64 * 32;
    const float* W2k = Wh2 + (size_t)role * 32 * 32;
    float4 a1 = *(const float4*)(bh1 + role * 32 + n0);
#pragma unroll 8
    for (int j = 0; j < 64; ++j) {
      float hj = b2f(h0s[r * 68 + j]);
      float4 wv = *(const float4*)(W1k + j * 32 + n0);
      a1.x += hj * wv.x; a1.y += hj * wv.y; a1.z += hj * wv.z; a1.w += hj * wv.w;
    }
    h1s[r * 36 + n0 + 0] = fmaxf(a1.x, 0.f);
    h1s[r * 36 + n0 + 1] = fmaxf(a1.y, 0.f);
    h1s[r * 36 + n0 + 2] = fmaxf(a1.z, 0.f);
    h1s[r * 36 + n0 + 3] = fmaxf(a1.w, 0.f);
    __syncthreads();
    float4 a2 = *(const float4*)(bh2 + role * 32 + n0);
#pragma unroll 8
    for (int n = 0; n < 32; ++n) {
      float hn = h1s[r * 36 + n];
      float4 wv = *(const float4*)(W2k + n * 32 + n0);
      a2.x += hn * wv.x; a2.y += hn * wv.y; a2.z += hn * wv.z; a2.w += hn * wv.w;
    }
    if (valid) {
      int g = bucket[roleBase + rowBase + r];
      float4 av = *(const float4*)(avail + (size_t)g * 32 + n0);
      float4 o;
      o.x = (av.x > 0.5f) ? a2.x : -1e10f;
      o.y = (av.y > 0.5f) ? a2.y : -1e10f;
      o.z = (av.z > 0.5f) ? a2.z : -1e10f;
      o.w = (av.w > 0.5f) ? a2.w : -1e10f;
      *(float4*)(outLogits + (size_t)g * 32 + n0) = o;
    }
  }
}

// ---------------------------------------------------------------- launcher
extern "C" void kernel_launch(void* const* d_in, const int* in_sizes, int n_in,
                              void* d_out, int out_size, void* d_ws, size_t ws_size,
                              hipStream_t stream)
{
  const float* rnn  = (const float*)d_in[0];
  const float* obs  = (const float*)d_in[1];
  const float* avail= (const float*)d_in[3];
  const int*   rid  = (const int*)d_in[4];
  const float* fn_s = (const float*)d_in[5];
  const float* fn_b = (const float*)d_in[6];
  const float* W0   = (const float*)d_in[7];
  const float* b0   = (const float*)d_in[8];
  const float* ln0s = (const float*)d_in[9];
  const float* ln0b = (const float*)d_in[10];
  const float* W1   = (const float*)d_in[11];
  const float* b1   = (const float*)d_in[12];
  const float* ln1s = (const float*)d_in[13];
  const float* ln1b = (const float*)d_in[14];
  const float* Wr0  = (const float*)d_in[15];
  const float* br0  = (const float*)d_in[16];
  const float* Wr1  = (const float*)d_in[17];
  const float* br1  = (const float*)d_in[18];
  const float* Wh0  = (const float*)d_in[19];
  const float* bh0  = (const float*)d_in[20];
  const float* Wh1  = (const float*)d_in[21];
  const float* bh1  = (const float*)d_in[22];
  const float* Wh2  = (const float*)d_in[23];
  const float* bh2  = (const float*)d_in[24];

  const int ROWS = 32768;

  char* w = (char*)d_ws;
  auto carve = [&](size_t bytes) { char* p = w; w += (bytes + 255) & ~(size_t)255; return p; };
  u16* obs_n  = (u16*)carve((size_t)ROWS * 256 * 2);
  u16* bufA   = (u16*)carve((size_t)ROWS * 512 * 2);   // e0
  u16* bufB   = (u16*)carve((size_t)ROWS * 512 * 2);   // e
  u16* W0t    = (u16*)carve((size_t)512 * 256 * 2);
  u16* W1t    = (u16*)carve((size_t)512 * 512 * 2);
  u16* Wr0t   = (u16*)carve((size_t)6 * 128 * 256 * 2);
  u16* Wr1t   = (u16*)carve((size_t)6 * 512 * 128 * 2);
  u16* Wh0t   = (u16*)carve((size_t)6 * 64 * 512 * 2);
  int* bucket = (int*)carve((size_t)ROWS * 4);
  int* blkCnt = (int*)carve((size_t)128 * NROLE * 4);
  int* blkBase= (int*)carve((size_t)128 * NROLE * 4);
  int* baseArr= (int*)carve(256);
  int* cntArr = (int*)carve(256);

  float* outLogits = (float*)d_out + (size_t)1024 * 512;

  hipMemcpyAsync(d_out, rnn, (size_t)1024 * 512 * 4, hipMemcpyDeviceToDevice, stream);

  transpose_all<<<1152, 256, 0, stream>>>(W0, W1, Wr0, Wr1, Wh0, W0t, W1t, Wr0t, Wr1t, Wh0t);

  ln_f32_256<<<8192, 256, 0, stream>>>(obs, fn_s, fn_b, obs_n, ROWS);

  role_count<<<128, 256, 0, stream>>>(rid, blkCnt);
  role_scan<<<1, 256, 0, stream>>>(blkCnt, blkBase, baseArr, cntArr);
  role_fill<<<128, 256, 0, stream>>>(rid, blkBase, bucket);

  // base MLP, LN fused + software-pipelined
  gemm_ln<256><<<512, 256, 0, stream>>>(obs_n, W0t, b0, ln0s, ln0b, bufA);
  gemm_ln<512><<<512, 256, 0, stream>>>(bufA, W1t, b1, ln1s, ln1b, bufB);

  // fused role route + full head (writes final logits)
  route_head<<<1029, 256, 0, stream>>>(obs_n, bufB, Wr0t, br0, Wr1t, br1, Wh0t, bh0,
                                       Wh1, bh1, Wh2, bh2, avail,
                                       bucket, baseArr, cntArr, outLogits);
}

// Round 8
// 267.549 us; speedup vs baseline: 1.0489x; 1.0489x over previous
//
#include <hip/hip_runtime.h>
#include <stdint.h>

typedef unsigned short u16;
typedef unsigned int u32;

using bf16x8 = __attribute__((ext_vector_type(8))) short;
using f32x4  = __attribute__((ext_vector_type(4))) float;

#define DEVINL __device__ __forceinline__

DEVINL float b2f(u16 u) { return __builtin_bit_cast(float, (u32)u << 16); }
DEVINL u16 f2b(float f) {
  u32 u = __builtin_bit_cast(u32, f);
  u += 0x7FFFu + ((u >> 16) & 1u);   // round-to-nearest-even
  return (u16)(u >> 16);
}

DEVINL void gll16(const u16* src, u16* dst) {
  __builtin_amdgcn_global_load_lds(
      (const __attribute__((address_space(1))) void*)(uintptr_t)src,
      (__attribute__((address_space(3))) void*)(uintptr_t)dst, 16, 0, 0);
}

#define MFMA __builtin_amdgcn_mfma_f32_16x16x32_bf16
#define NROLE 6

// ---------------------------------------------------------------- mega0:
// transposes (blocks 0..1151) | obs-LN (1152..3199) | role_count (3200..3327)
// | rnn passthrough copy (3328..3455). All independent.
DEVINL void tp_tile(const float* __restrict__ s, u16* __restrict__ d,
                    int R, int C, int bx, int by, int z)
{
  __shared__ u16 tile[32][33];
  const size_t mstride = (size_t)R * C;
  s += (size_t)z * mstride;
  d += (size_t)z * mstride;
  int r0 = bx * 32, c0 = by * 32;
  int tx = threadIdx.x & 31, ty = threadIdx.x >> 5;
#pragma unroll
  for (int i = 0; i < 32; i += 8)
    tile[ty + i][tx] = f2b(s[(size_t)(r0 + ty + i) * C + (c0 + tx)]);
  __syncthreads();
#pragma unroll
  for (int i = 0; i < 32; i += 8)
    d[(size_t)(c0 + ty + i) * R + (r0 + tx)] = tile[tx][ty + i];
}

__global__ __launch_bounds__(256) void mega0(
    const float* W0, const float* W1, const float* Wr0, const float* Wr1, const float* Wh0,
    u16* W0t, u16* W1t, u16* Wr0t, u16* Wr1t, u16* Wh0t,
    const float* __restrict__ obs, const float* __restrict__ fn_s,
    const float* __restrict__ fn_b, u16* __restrict__ obs_n,
    const int* __restrict__ rid, int* __restrict__ blkCnt,
    const float* __restrict__ rnn, float* __restrict__ outRnn)
{
  int b = blockIdx.x;
  const int tid = threadIdx.x;
  if (b < 1152) {
    if (b < 128)      {            tp_tile(W0, W0t, 256, 512, b % 8,  b / 8, 0); }
    else if (b < 384) { b -= 128;  tp_tile(W1, W1t, 512, 512, b % 16, b / 16, 0); }
    else if (b < 576) { b -= 384;  int t = b / 8;  tp_tile(Wr0, Wr0t, 256, 128, b % 8,  t % 4,  t / 4); }
    else if (b < 960) { b -= 576;  int t = b / 4;  tp_tile(Wr1, Wr1t, 128, 512, b % 4,  t % 16, t / 16); }
    else              { b -= 960;  int t = b / 16; tp_tile(Wh0, Wh0t, 512, 64,  b % 16, t % 2,  t / 2); }
  } else if (b < 3200) {
    // obs layernorm: 16 rows per block (4 waves x 4 rows)
    b -= 1152;
    const int lane = tid & 63, wave = tid >> 6;
#pragma unroll
    for (int it = 0; it < 4; ++it) {
      int row = b * 16 + wave * 4 + it;
      const float* xr = obs + (size_t)row * 256 + lane * 4;
      float x[4] __attribute__((aligned(16)));
      *(float4*)x = *(const float4*)xr;
      float s = 0.f, s2 = 0.f;
#pragma unroll
      for (int p = 0; p < 4; ++p) { s += x[p]; s2 += x[p] * x[p]; }
#pragma unroll
      for (int o = 32; o > 0; o >>= 1) { s += __shfl_xor(s, o, 64); s2 += __shfl_xor(s2, o, 64); }
      float m = s * (1.f / 256.f);
      float v = s2 * (1.f / 256.f) - m * m;
      float inv = rsqrtf(v + 1e-5f);
      u16 yu[4] __attribute__((aligned(8)));
#pragma unroll
      for (int p = 0; p < 4; ++p)
        yu[p] = f2b((x[p] - m) * inv * fn_s[lane * 4 + p] + fn_b[lane * 4 + p]);
      *(uint2*)(obs_n + (size_t)row * 256 + lane * 4) = *(uint2*)yu;
    }
  } else if (b < 3328) {
    b -= 3200;
    __shared__ int h[NROLE];
    if (tid < NROLE) h[tid] = 0;
    __syncthreads();
    atomicAdd(&h[rid[b * 256 + tid]], 1);
    __syncthreads();
    if (tid < NROLE) blkCnt[b * NROLE + tid] = h[tid];
  } else {
    b -= 3328;
    const float4* src = (const float4*)rnn;
    float4* dst = (float4*)outRnn;
    int base = (b * 256 + tid) * 4;
#pragma unroll
    for (int i = 0; i < 4; ++i) dst[base + i] = src[base + i];
  }
}

// ---------------------------------------------------------------- fill2: scan (redundant per block) + fill
__global__ __launch_bounds__(256) void fill2(
    const int* __restrict__ rid, const int* __restrict__ blkCnt,
    int* __restrict__ bucket, int* __restrict__ baseArr, int* __restrict__ cntArr)
{
  __shared__ int c[128 * NROLE];
  __shared__ int preArr[NROLE], scnt[NROLE], sbase[NROLE], h[NROLE];
  const int tid = threadIdx.x;
  const int bx = blockIdx.x;
  for (int i = tid; i < 128 * NROLE; i += 256) c[i] = blkCnt[i];
  if (tid < NROLE) h[tid] = 0;
  __syncthreads();
  if (tid < NROLE) {
    int k = tid, run = 0, pre = 0;
    for (int b = 0; b < 128; ++b) { if (b == bx) pre = run; run += c[b * NROLE + k]; }
    scnt[k] = run; preArr[k] = pre;
  }
  __syncthreads();
  if (tid == 0) {
    int r = 0;
    for (int k = 0; k < NROLE; ++k) { sbase[k] = r; r += scnt[k]; }
  }
  __syncthreads();
  if (bx == 0 && tid < NROLE) { baseArr[tid] = sbase[tid]; cntArr[tid] = scnt[tid]; }
  int i = bx * 256 + tid;
  int k = rid[i];
  int pos = atomicAdd(&h[k], 1);
  bucket[sbase[k] + preArr[k] + pos] = i;
}

// ---------------------------------------------------------------- fused dense GEMM + ReLU + LN
// BM=64, 4 waves x 128 cols, acc[4][8]; A dbuf in LDS, B reg-prefetched from global.
template <int K>
__global__ __launch_bounds__(256, 2) void gemm_ln(
    const u16* __restrict__ A, const u16* __restrict__ Bt,
    const float* __restrict__ bias, const float* __restrict__ lnsc,
    const float* __restrict__ lnbi, u16* __restrict__ C)
{
  constexpr int BK = 64, NI = K / BK;
  __shared__ __align__(16) u16 As[2][64 * BK];
  __shared__ float redS[64][4];
  __shared__ float redSS[64][4];
  __shared__ float prm[1536];
  const int tid = threadIdx.x;
  const int rowBase = blockIdx.x * 64;
  const int lane = tid & 63, wave = tid >> 6;
#pragma unroll
  for (int i = tid; i < 512; i += 256) {
    prm[i] = bias[i]; prm[512 + i] = lnsc[i]; prm[1024 + i] = lnbi[i];
  }
  u32 aOff[2];
#pragma unroll
  for (int r = 0; r < 2; ++r) {
    int row = r * 32 + (tid >> 3);
    aOff[r] = (u32)(rowBase + row) * (u32)K + (u32)(((tid & 7) ^ (row & 7)) * 8);
  }
  const int quad = lane >> 4, lm = lane & 15, l7 = lm & 7;
  const int wn = wave * 128;
  u32 bOff[8];
#pragma unroll
  for (int j = 0; j < 8; ++j)
    bOff[j] = (u32)(wn + j * 16 + lm) * (u32)K + (u32)(quad * 8);

  f32x4 acc[4][8] = {};

#pragma unroll
  for (int r = 0; r < 2; ++r)
    gll16(A + aOff[r], &As[0][r * 2048 + wave * 512]);
  bf16x8 bP[8];
#pragma unroll
  for (int j = 0; j < 8; ++j)
    bP[j] = *(const bf16x8*)(Bt + bOff[j]);
  __syncthreads();

  for (int i = 0; i < NI; ++i) {
    const u16* Ab = As[i & 1];
    if (i + 1 < NI) {
#pragma unroll
      for (int r = 0; r < 2; ++r)
        gll16(A + aOff[r] + (i + 1) * BK, &As[(i + 1) & 1][r * 2048 + wave * 512]);
    }
    bf16x8 bN[8];
#pragma unroll
    for (int j = 0; j < 8; ++j)
      bN[j] = *(const bf16x8*)(Bt + bOff[j] + i * BK + 32);
    bf16x8 af[4];
#pragma unroll
    for (int i2 = 0; i2 < 4; ++i2)
      af[i2] = *(const bf16x8*)&Ab[(i2 * 16 + lm) * 64 + ((quad ^ l7) * 8)];
#pragma unroll
    for (int i2 = 0; i2 < 4; ++i2)
#pragma unroll
      for (int j = 0; j < 8; ++j)
        acc[i2][j] = MFMA(af[i2], bP[j], acc[i2][j], 0, 0, 0);
    if (i + 1 < NI) {
#pragma unroll
      for (int j = 0; j < 8; ++j)
        bP[j] = *(const bf16x8*)(Bt + bOff[j] + (i + 1) * BK);
    }
#pragma unroll
    for (int i2 = 0; i2 < 4; ++i2)
      af[i2] = *(const bf16x8*)&Ab[(i2 * 16 + lm) * 64 + (((quad + 4) ^ l7) * 8)];
#pragma unroll
    for (int i2 = 0; i2 < 4; ++i2)
#pragma unroll
      for (int j = 0; j < 8; ++j)
        acc[i2][j] = MFMA(af[i2], bN[j], acc[i2][j], 0, 0, 0);
    __syncthreads();
  }

#pragma unroll
  for (int i2 = 0; i2 < 4; ++i2) {
#pragma unroll
    for (int r2 = 0; r2 < 4; ++r2) {
      float s = 0.f, ss = 0.f;
#pragma unroll
      for (int j = 0; j < 8; ++j) {
        float v = fmaxf(acc[i2][j][r2] + prm[wn + j * 16 + lm], 0.f);
        acc[i2][j][r2] = v;
        s += v; ss += v * v;
      }
#pragma unroll
      for (int o = 1; o < 16; o <<= 1) { s += __shfl_xor(s, o, 64); ss += __shfl_xor(ss, o, 64); }
      if (lm == 0) {
        int rowL = i2 * 16 + quad * 4 + r2;
        redS[rowL][wave] = s;
        redSS[rowL][wave] = ss;
      }
    }
  }
  __syncthreads();
#pragma unroll
  for (int i2 = 0; i2 < 4; ++i2) {
#pragma unroll
    for (int r2 = 0; r2 < 4; ++r2) {
      int rowL = i2 * 16 + quad * 4 + r2;
      float ts  = redS[rowL][0] + redS[rowL][1] + redS[rowL][2] + redS[rowL][3];
      float tss = redSS[rowL][0] + redSS[rowL][1] + redSS[rowL][2] + redSS[rowL][3];
      float m = ts * (1.f / 512.f);
      float var = tss * (1.f / 512.f) - m * m;
      float inv = rsqrtf(var + 1e-5f);
      size_t base = (size_t)(rowBase + rowL) * 512;
#pragma unroll
      for (int j = 0; j < 8; ++j) {
        int col = wn + j * 16 + lm;
        float y = (acc[i2][j][r2] - m) * inv * prm[512 + col] + prm[1024 + col];
        C[base + col] = f2b(y);
      }
    }
  }
}

// ---------------------------------------------------------------- fused role route + head
// LDS (u16 idx): e/ea [0,16384) | A0 [16384,24576)
//   aliases after stage0: r1 [16384,20480), h0s [20480,22656), h1s(f32) [22656,24960)
// 51.5 KB total -> 3 blocks/CU.
__global__ __launch_bounds__(256, 3) void route_head(
    const u16* __restrict__ obs_n, const u16* __restrict__ e,
    const u16* __restrict__ Wr0t, const float* __restrict__ br0,
    const u16* __restrict__ Wr1t, const float* __restrict__ br1,
    const u16* __restrict__ Wh0t, const float* __restrict__ bh0,
    const float* __restrict__ Wh1, const float* __restrict__ bh1,
    const float* __restrict__ Wh2, const float* __restrict__ bh2,
    const float* __restrict__ avail,
    const int* __restrict__ bucket, const int* __restrict__ baseArr,
    const int* __restrict__ cntArr, float* __restrict__ outLogits)
{
  __shared__ __align__(16) u16 sm[24960];
  __shared__ float prm[704];        // br0 128 | br1 512 | bh0 64
  const int tid = threadIdx.x;

  int role = 0, rem = blockIdx.x, cnt;
  for (;;) {
    cnt = cntArr[role];
    int tiles = (cnt + 31) >> 5;
    if (rem < tiles) break;
    rem -= tiles;
    if (++role >= NROLE) return;
  }
  const int limit = cnt;
  const int rowBase = rem * 32;
  const int roleBase = baseArr[role];

  const int lane = tid & 63, wave = tid >> 6;
  const int quad = lane >> 4, lm = lane & 15, l7 = lm & 7;

  // ---- stage A0 (32x256 obs_n) -> sm[16384..)
#pragma unroll
  for (int r = 0; r < 4; ++r) {
    int lrow = r * 8 + (tid >> 5);
    int i = rowBase + lrow;
    if (i >= limit) i = rowBase;
    int grow = bucket[roleBase + i];
    gll16(obs_n + (u32)grow * 256u + (u32)(((tid & 31) ^ (lrow & 7)) * 8),
          &sm[16384 + r * 2048 + wave * 512]);
  }
  // ---- stage e (32x512) -> sm[0..16384)
#pragma unroll
  for (int r = 0; r < 8; ++r) {
    int lrow = r * 4 + wave;
    int i = rowBase + lrow;
    if (i >= limit) i = rowBase;
    int grow = bucket[roleBase + i];
    int chunk = tid & 63;
    int sw = (chunk & 56) | ((chunk ^ lrow) & 7);
    gll16(e + (u32)grow * 512u + (u32)(sw * 8), &sm[r * 2048 + wave * 512]);
  }
  {
    if (tid < 128) prm[tid] = br0[role * 128 + tid];
    for (int i = tid; i < 512; i += 256) prm[128 + i] = br1[role * 512 + i];
    if (tid < 64) prm[640 + tid] = bh0[role * 64 + tid];
  }
  __syncthreads();   // drain all staging

  // ---- stage0: r1 = relu(A0 @ Wr0k^T + br0)  (N=128; wave = 32 cols); B ring-2
  const int wn0 = wave * 32;
  const u16* B0 = Wr0t + (size_t)role * 128 * 256;
  f32x4 acc0[2][2] = {};
  bf16x8 b0R[2][2];
#pragma unroll
  for (int p = 0; p < 2; ++p)
#pragma unroll
    for (int j = 0; j < 2; ++j)
      b0R[p][j] = *(const bf16x8*)(B0 + (u32)(wn0 + j * 16 + lm) * 256u + (u32)(quad * 8 + p * 32));
#pragma unroll
  for (int it = 0; it < 8; ++it) {
    bf16x8 cur0 = b0R[it & 1][0], cur1 = b0R[it & 1][1];
    if (it + 2 < 8) {
#pragma unroll
      for (int j = 0; j < 2; ++j)
        b0R[it & 1][j] = *(const bf16x8*)(B0 + (u32)(wn0 + j * 16 + lm) * 256u + (u32)(quad * 8 + (it + 2) * 32));
    }
    const int kc = it * 4;
    bf16x8 af[2];
#pragma unroll
    for (int i2 = 0; i2 < 2; ++i2)
      af[i2] = *(const bf16x8*)&sm[16384 + (i2 * 16 + lm) * 256 + (((quad + kc) ^ l7) * 8)];
#pragma unroll
    for (int i2 = 0; i2 < 2; ++i2) {
      acc0[i2][0] = MFMA(af[i2], cur0, acc0[i2][0], 0, 0, 0);
      acc0[i2][1] = MFMA(af[i2], cur1, acc0[i2][1], 0, 0, 0);
    }
  }
  __syncthreads();   // all A0 reads done before r1 aliases A0 space
  u16* r1 = sm + 16384;
#pragma unroll
  for (int i2 = 0; i2 < 2; ++i2) {
#pragma unroll
    for (int r2 = 0; r2 < 4; ++r2) {
      int row = i2 * 16 + quad * 4 + r2;
#pragma unroll
      for (int j = 0; j < 2; ++j) {
        int col = wn0 + j * 16 + lm;
        float v = fmaxf(acc0[i2][j][r2] + prm[col], 0.f);
        r1[row * 128 + (((col >> 3) ^ (row & 7)) * 8) + (col & 7)] = f2b(v);
      }
    }
  }
  __syncthreads();

  // ---- stage1: ea = relu(r1 @ Wr1k^T + br1) + e  (in-place over e)
  const int wn1 = wave * 128;
  const u16* B1 = Wr1t + (size_t)role * 512 * 128;
  f32x4 acc1[2][8] = {};
  bf16x8 b1P[8];
#pragma unroll
  for (int j = 0; j < 8; ++j)
    b1P[j] = *(const bf16x8*)(B1 + (u32)(wn1 + j * 16 + lm) * 128u + (u32)(quad * 8));
#pragma unroll
  for (int kk = 0; kk < 128; kk += 32) {
    bf16x8 b1N[8];
    if (kk + 32 < 128) {
#pragma unroll
      for (int j = 0; j < 8; ++j)
        b1N[j] = *(const bf16x8*)(B1 + (u32)(wn1 + j * 16 + lm) * 128u + (u32)(quad * 8 + kk + 32));
    }
    const int kc = kk >> 3;
    bf16x8 af[2];
#pragma unroll
    for (int i2 = 0; i2 < 2; ++i2)
      af[i2] = *(const bf16x8*)&r1[(i2 * 16 + lm) * 128 + (((quad + kc) ^ l7) * 8)];
#pragma unroll
    for (int i2 = 0; i2 < 2; ++i2)
#pragma unroll
      for (int j = 0; j < 8; ++j)
        acc1[i2][j] = MFMA(af[i2], b1P[j], acc1[i2][j], 0, 0, 0);
    if (kk + 32 < 128) {
#pragma unroll
      for (int j = 0; j < 8; ++j) b1P[j] = b1N[j];
    }
  }
#pragma unroll
  for (int i2 = 0; i2 < 2; ++i2) {
#pragma unroll
    for (int r2 = 0; r2 < 4; ++r2) {
      int row = i2 * 16 + quad * 4 + r2;
#pragma unroll
      for (int j = 0; j < 8; ++j) {
        int col = wn1 + j * 16 + lm;
        int addr = row * 512 + (((col >> 3) ^ (row & 7)) * 8) + (col & 7);
        float v = fmaxf(acc1[i2][j][r2] + prm[128 + col], 0.f) + b2f(sm[addr]);
        sm[addr] = f2b(v);
      }
    }
  }
  __syncthreads();

  // ---- stage2: h0 = relu(ea @ Wh0k^T + bh0)  (N=64; wave = 16 cols); B ring-4
  const int wn2 = wave * 16;
  const u16* B2 = Wh0t + (size_t)role * 64 * 512;
  f32x4 acc2[2] = {};
  bf16x8 b2R[4];
#pragma unroll
  for (int p = 0; p < 4; ++p)
    b2R[p] = *(const bf16x8*)(B2 + (u32)(wn2 + lm) * 512u + (u32)(quad * 8 + p * 32));
#pragma unroll
  for (int it = 0; it < 16; ++it) {
    bf16x8 cur = b2R[it & 3];
    if (it + 4 < 16)
      b2R[it & 3] = *(const bf16x8*)(B2 + (u32)(wn2 + lm) * 512u + (u32)(quad * 8 + (it + 4) * 32));
    const int kc = it * 4;
    bf16x8 af[2];
#pragma unroll
    for (int i2 = 0; i2 < 2; ++i2)
      af[i2] = *(const bf16x8*)&sm[(i2 * 16 + lm) * 512 + (((quad + kc) ^ l7) * 8)];
#pragma unroll
    for (int i2 = 0; i2 < 2; ++i2)
      acc2[i2] = MFMA(af[i2], cur, acc2[i2], 0, 0, 0);
  }
  u16* h0s = sm + 20480;   // r1 region, dead; 32 rows x stride 68
#pragma unroll
  for (int i2 = 0; i2 < 2; ++i2) {
#pragma unroll
    for (int r2 = 0; r2 < 4; ++r2) {
      int row = i2 * 16 + quad * 4 + r2;
      int col = wn2 + lm;
      h0s[row * 68 + col] = f2b(fmaxf(acc2[i2][r2] + prm[640 + col], 0.f));
    }
  }
  __syncthreads();

  // ---- stage3: per-thread tail. thread t -> row r=t>>3, 4 cols n0=(t&7)*4
  {
    float* h1s = (float*)&sm[22656];   // 32 x 36 f32
    const int r = tid >> 3;
    const int n0 = (tid & 7) * 4;
    const bool valid = (rowBase + r) < limit;
    const float* W1k = Wh1 + (size_t)role * 64 * 32;
    const float* W2k = Wh2 + (size_t)role * 32 * 32;
    float4 a1 = *(const float4*)(bh1 + role * 32 + n0);
#pragma unroll 8
    for (int j = 0; j < 64; ++j) {
      float hj = b2f(h0s[r * 68 + j]);
      float4 wv = *(const float4*)(W1k + j * 32 + n0);
      a1.x += hj * wv.x; a1.y += hj * wv.y; a1.z += hj * wv.z; a1.w += hj * wv.w;
    }
    h1s[r * 36 + n0 + 0] = fmaxf(a1.x, 0.f);
    h1s[r * 36 + n0 + 1] = fmaxf(a1.y, 0.f);
    h1s[r * 36 + n0 + 2] = fmaxf(a1.z, 0.f);
    h1s[r * 36 + n0 + 3] = fmaxf(a1.w, 0.f);
    __syncthreads();
    float4 a2 = *(const float4*)(bh2 + role * 32 + n0);
#pragma unroll 8
    for (int n = 0; n < 32; ++n) {
      float hn = h1s[r * 36 + n];
      float4 wv = *(const float4*)(W2k + n * 32 + n0);
      a2.x += hn * wv.x; a2.y += hn * wv.y; a2.z += hn * wv.z; a2.w += hn * wv.w;
    }
    if (valid) {
      int g = bucket[roleBase + rowBase + r];
      float4 av = *(const float4*)(avail + (size_t)g * 32 + n0);
      float4 o;
      o.x = (av.x > 0.5f) ? a2.x : -1e10f;
      o.y = (av.y > 0.5f) ? a2.y : -1e10f;
      o.z = (av.z > 0.5f) ? a2.z : -1e10f;
      o.w = (av.w > 0.5f) ? a2.w : -1e10f;
      *(float4*)(outLogits + (size_t)g * 32 + n0) = o;
    }
  }
}

// ---------------------------------------------------------------- launcher
extern "C" void kernel_launch(void* const* d_in, const int* in_sizes, int n_in,
                              void* d_out, int out_size, void* d_ws, size_t ws_size,
                              hipStream_t stream)
{
  const float* rnn  = (const float*)d_in[0];
  const float* obs  = (const float*)d_in[1];
  const float* avail= (const float*)d_in[3];
  const int*   rid  = (const int*)d_in[4];
  const float* fn_s = (const float*)d_in[5];
  const float* fn_b = (const float*)d_in[6];
  const float* W0   = (const float*)d_in[7];
  const float* b0   = (const float*)d_in[8];
  const float* ln0s = (const float*)d_in[9];
  const float* ln0b = (const float*)d_in[10];
  const float* W1   = (const float*)d_in[11];
  const float* b1   = (const float*)d_in[12];
  const float* ln1s = (const float*)d_in[13];
  const float* ln1b = (const float*)d_in[14];
  const float* Wr0  = (const float*)d_in[15];
  const float* br0  = (const float*)d_in[16];
  const float* Wr1  = (const float*)d_in[17];
  const float* br1  = (const float*)d_in[18];
  const float* Wh0  = (const float*)d_in[19];
  const float* bh0  = (const float*)d_in[20];
  const float* Wh1  = (const float*)d_in[21];
  const float* bh1  = (const float*)d_in[22];
  const float* Wh2  = (const float*)d_in[23];
  const float* bh2  = (const float*)d_in[24];

  const int ROWS = 32768;

  char* w = (char*)d_ws;
  auto carve = [&](size_t bytes) { char* p = w; w += (bytes + 255) & ~(size_t)255; return p; };
  u16* obs_n  = (u16*)carve((size_t)ROWS * 256 * 2);
  u16* bufA   = (u16*)carve((size_t)ROWS * 512 * 2);   // e0
  u16* bufB   = (u16*)carve((size_t)ROWS * 512 * 2);   // e
  u16* W0t    = (u16*)carve((size_t)512 * 256 * 2);
  u16* W1t    = (u16*)carve((size_t)512 * 512 * 2);
  u16* Wr0t   = (u16*)carve((size_t)6 * 128 * 256 * 2);
  u16* Wr1t   = (u16*)carve((size_t)6 * 512 * 128 * 2);
  u16* Wh0t   = (u16*)carve((size_t)6 * 64 * 512 * 2);
  int* bucket = (int*)carve((size_t)ROWS * 4);
  int* blkCnt = (int*)carve((size_t)128 * NROLE * 4);
  int* baseArr= (int*)carve(256);
  int* cntArr = (int*)carve(256);

  float* outLogits = (float*)d_out + (size_t)1024 * 512;

  // mega0: weight transposes + obs-LN + role_count + rnn passthrough
  mega0<<<3456, 256, 0, stream>>>(W0, W1, Wr0, Wr1, Wh0, W0t, W1t, Wr0t, Wr1t, Wh0t,
                                  obs, fn_s, fn_b, obs_n, rid, blkCnt, rnn, (float*)d_out);

  // scan+fill in one dispatch
  fill2<<<128, 256, 0, stream>>>(rid, blkCnt, bucket, baseArr, cntArr);

  // base MLP, LN fused + pipelined
  gemm_ln<256><<<512, 256, 0, stream>>>(obs_n, W0t, b0, ln0s, ln0b, bufA);
  gemm_ln<512><<<512, 256, 0, stream>>>(bufA, W1t, b1, ln1s, ln1b, bufB);

  // fused role route + full head
  route_head<<<1029, 256, 0, stream>>>(obs_n, bufB, Wr0t, br0, Wr1t, br1, Wh0t, bh0,
                                       Wh1, bh1, Wh2, bh2, avail,
                                       bucket, baseArr, cntArr, outLogits);
}